// Round 14
// baseline (1062.499 us; speedup 1.0000x reference)
//
#include <hip/hip_runtime.h>
#include <hip/hip_fp16.h>

#define NN 50000
#define TT 12
#define EE 800000
#define IN_C 32
#define HID 64
#define OUT_C 32
#define BSZ 64                        // nodes per bucket
#define NB ((NN + BSZ - 1) / BSZ)     // 782
#define CAP 1600                      // slots per (t,bucket); mean 1024
#define EPB 8192                      // edges per bin block
#define ABLK ((EE + EPB - 1) / EPB)   // 98
#define GNB 16                        // nodes per gate block (NN/GNB = 3125 exact)
#define XPAIRS ((size_t)TT * NN * 16) // half2 elements in x

// ---------------- precompute folded gate matrices ----------------
// Mz = Wz @ Lz_w[:64] (32x64), Bz = bz @ Lz_w[:64] + Lz_b (64); same for h.
__global__ __launch_bounds__(64) void prep_kernel(
    const float* __restrict__ Wz, const float* __restrict__ bz,
    const float* __restrict__ Lzw, const float* __restrict__ Lzb,
    const float* __restrict__ Wh, const float* __restrict__ bh,
    const float* __restrict__ Lhw, const float* __restrict__ Lhb,
    float* __restrict__ Mz, float* __restrict__ Bz,
    float* __restrict__ Mh, float* __restrict__ Bh) {
  const int j = threadIdx.x;
  const int i = blockIdx.x;
  const int h = blockIdx.y;
  const float* W  = h ? Wh  : Wz;
  const float* b  = h ? bh  : bz;
  const float* L  = h ? Lhw : Lzw;
  const float* Lb = h ? Lhb : Lzb;
  float* M = h ? Mh : Mz;
  float* B = h ? Bh : Bz;
  if (i < IN_C) {
    float v = 0.f;
    for (int k = 0; k < HID; ++k) v += W[i * HID + k] * L[k * HID + j];
    M[i * HID + j] = v;
  } else {
    float v = Lb[j];
    for (int k = 0; k < HID; ++k) v += b[k] * L[k * HID + j];
    B[j] = v;
  }
}

// x [T,N,32] fp32 -> fp16 pairs
__global__ __launch_bounds__(256) void xconv_kernel(const float* __restrict__ x,
                                                    __half2* __restrict__ xh) {
  size_t i = (size_t)blockIdx.x * 256 + threadIdx.x;
  if (i < XPAIRS) {
    float2 f = ((const float2*)x)[i];
    xh[i] = __floats2half2_rn(f.x, f.y);
  }
}

// Pass A: coarse-bucket multisplit (proven R8-R13).
// Entries {src16 | (dst&63)<<16 | w16<<32} bucket-grouped.
__global__ __launch_bounds__(256) void bin_kernel(const int* __restrict__ ei,
                                                  const float* __restrict__ ew,
                                                  int* __restrict__ cursorA,
                                                  unsigned long long* __restrict__ binA,
                                                  int tbase) {
  __shared__ int hist[NB];
  __shared__ int rnk[NB];
  int tl = blockIdx.y;
  const int* src = ei + (size_t)(tbase + tl) * 2 * EE;
  const int* dst = src + EE;
  const float* w = ew + (size_t)(tbase + tl) * EE;
  int* cursor = cursorA + (size_t)tl * NB;
  unsigned long long* bin = binA + (size_t)tl * NB * CAP;
  int t = threadIdx.x;
  for (int i = t; i < NB; i += 256) { hist[i] = 0; rnk[i] = 0; }
  __syncthreads();
  int e0 = blockIdx.x * EPB;
#pragma unroll
  for (int i = 0; i < EPB / 256; ++i) {
    int e = e0 + i * 256 + t;
    if (e < EE) atomicAdd(&hist[dst[e] >> 6], 1);
  }
  __syncthreads();
  for (int b = t; b < NB; b += 256)
    hist[b] = atomicAdd(&cursor[b], hist[b]);  // hist becomes this block's base
  __syncthreads();
#pragma unroll
  for (int i = 0; i < EPB / 256; ++i) {
    int e = e0 + i * 256 + t;
    if (e < EE) {
      int d = dst[e], s = src[e];
      int b = d >> 6;
      unsigned short hw = __half_as_ushort(__float2half_rn(w[e]));
      int pos = hist[b] + atomicAdd(&rnk[b], 1);
      if (pos < CAP)
        bin[(size_t)b * CAP + pos] =
            (unsigned long long)((unsigned)s | ((unsigned)(d & 63) << 16)) |
            ((unsigned long long)hw << 32);
    }
  }
}

// per (bucket,t): deg = 1 + sum w over bucket entries, dinv = rsqrt(deg)
__global__ __launch_bounds__(256) void deg_kernel(const int* __restrict__ cursorA,
                                                  const unsigned long long* __restrict__ binA,
                                                  float* __restrict__ dinvA) {
  __shared__ float wsum[BSZ];
  int tl = blockIdx.y, b = blockIdx.x;
  int t = threadIdx.x;
  if (t < BSZ) wsum[t] = 0.f;
  __syncthreads();
  int cnt = min(cursorA[(size_t)tl * NB + b], CAP);
  const unsigned long long* bin = binA + ((size_t)tl * NB + b) * CAP;
  for (int i = t; i < cnt; i += 256) {
    unsigned long long u = bin[i];
    int dl = (int)((u >> 16) & 63u);
    float wv = __half2float(__ushort_as_half((unsigned short)(u >> 32)));
    atomicAdd(&wsum[dl], wv);
  }
  __syncthreads();
  int n = b * BSZ + t;
  if (t < BSZ && n < NN) dinvA[(size_t)tl * NN + n] = rsqrtf(1.0f + wsum[t]);
}

// exclusive scan of clamped bucket counts -> bucket bases (per t)
__global__ __launch_bounds__(1024) void bscan_kernel(const int* __restrict__ cursorA,
                                                     int* __restrict__ bbaseA) {
  __shared__ int s[1024];
  int tl = blockIdx.x, t = threadIdx.x;
  int v = (t < NB) ? min(cursorA[(size_t)tl * NB + t], CAP) : 0;
  s[t] = v;
  __syncthreads();
  for (int o = 1; o < 1024; o <<= 1) {
    int u = (t >= o) ? s[t - o] : 0;
    __syncthreads();
    s[t] += u;
    __syncthreads();
  }
  if (t < NB) bbaseA[(size_t)tl * NB + t] = s[t] - v;  // exclusive
}

// per (bucket,t): counting-sort bucket entries by dst&63 into global CSR
// sbufG {src16 | fp16(w*dinv[src])<<16}; write noffG per node.
__global__ __launch_bounds__(256) void sort_kernel(
    const int* __restrict__ cursorA, const int* __restrict__ bbaseA,
    const unsigned long long* __restrict__ binA, const float* __restrict__ dinvA,
    unsigned* __restrict__ sbufG, int* __restrict__ noffG) {
  __shared__ int hist[BSZ + 1];
  __shared__ int plc[BSZ];
  int tl = blockIdx.y, b = blockIdx.x;
  int t = threadIdx.x;
  if (t < BSZ + 1) hist[t] = 0;
  __syncthreads();
  int cnt = min(cursorA[(size_t)tl * NB + b], CAP);
  int base = bbaseA[(size_t)tl * NB + b];
  const unsigned long long* bin = binA + ((size_t)tl * NB + b) * CAP;
  const float* dinv = dinvA + (size_t)tl * NN;
  unsigned* sbuf = sbufG + (size_t)tl * EE;
  int* noff = noffG + (size_t)tl * (NN + 1);
  for (int e = t; e < cnt; e += 256)
    atomicAdd(&hist[(int)((bin[e] >> 16) & 63u)], 1);
  __syncthreads();
  if (t == 0) {
    int run = 0;
#pragma unroll
    for (int i = 0; i < BSZ; ++i) {
      int c = hist[i];
      hist[i] = run;
      plc[i] = run;
      run += c;
    }
    hist[BSZ] = run;
    if (b == NB - 1) noff[NN] = base + run;
  }
  __syncthreads();
  {
    int n = b * BSZ + t;
    if (t < BSZ && n < NN) noff[n] = base + hist[t];
  }
  for (int e = t; e < cnt; e += 256) {
    unsigned long long u = bin[e];
    int s = (int)(u & 0xFFFFu);
    int dl = (int)((u >> 16) & 63u);
    float nm = __half2float(__ushort_as_half((unsigned short)(u >> 32))) * dinv[s];
    int pos = base + atomicAdd(&plc[dl], 1);
    sbuf[pos] = (unsigned)s | ((unsigned)__half_as_ushort(__float2half_rn(nm)) << 16);
  }
}

// Pass B1: pure gather, NO LDS / NO barriers (proven R13). t-major grid
// (blockIdx.y = t) keeps xh_t L2-resident. Wave = 2 nodes; writes y fp16.
__global__ __launch_bounds__(256) void gather_y_kernel(
    const float* __restrict__ x, const __half2* __restrict__ xh,
    const float* __restrict__ dinvA, const int* __restrict__ noffG,
    const unsigned* __restrict__ sbufG, __half2* __restrict__ yG, int tbase) {
  int t = threadIdx.x;
  int w = t >> 6;        // wave 0..3
  int lane = t & 63;
  int h2 = lane >> 5;    // node half 0/1
  int sl = lane & 31;
  int g = sl >> 3;       // edge group 0..3
  int cl = sl & 7;       // channel quad 0..7
  int tl = blockIdx.y;
  int n = blockIdx.x * 8 + w * 2 + h2;  // NN % 8 == 0, no tail

  const float* dinv = dinvA + (size_t)tl * NN;
  const int* noff = noffG + (size_t)tl * (NN + 1);
  const unsigned* sbuf = sbufG + (size_t)tl * EE;
  const __half2* xht = xh + (size_t)(tbase + tl) * NN * 16;
  const float* xt = x + (size_t)(tbase + tl) * NN * IN_C;

  int e0 = noff[n], e1 = noff[n + 1];
  float4 v = {0.f, 0.f, 0.f, 0.f};
  for (int e = e0 + g; e < e1; e += 4) {
    unsigned u = sbuf[e];  // 8 lanes same addr: broadcast
    float nm = __half2float(__ushort_as_half((unsigned short)(u >> 16)));
    uint2 xr = ((const uint2*)(xht + (size_t)(u & 0xFFFFu) * 16))[cl];
    float2 p0 = __half22float2(*(const __half2*)&xr.x);
    float2 p1 = __half22float2(*(const __half2*)&xr.y);
    v.x += nm * p0.x; v.y += nm * p0.y;
    v.z += nm * p1.x; v.w += nm * p1.y;
  }
  // reduce over the 4 edge groups (lane bits 3,4 — stays within node half)
  v.x += __shfl_xor(v.x, 8);  v.y += __shfl_xor(v.y, 8);
  v.z += __shfl_xor(v.z, 8);  v.w += __shfl_xor(v.w, 8);
  v.x += __shfl_xor(v.x, 16); v.y += __shfl_xor(v.y, 16);
  v.z += __shfl_xor(v.z, 16); v.w += __shfl_xor(v.w, 16);
  if (g == 0) {  // 8 lanes per node x float4 = all 32 channels
    float dv = dinv[n];
    float4 xs = ((const float4*)(xt + (size_t)n * IN_C))[cl];  // fp32 self-loop
    __half2 o0 = __floats2half2_rn(dv * (v.x + dv * xs.x), dv * (v.y + dv * xs.y));
    __half2 o1 = __floats2half2_rn(dv * (v.z + dv * xs.z), dv * (v.w + dv * xs.w));
    __half2* yp = yG + ((size_t)tl * NN + n) * 16 + cl * 2;
    yp[0] = o0;
    yp[1] = o1;
  }
}

// Pass B2: gate + accumulate, regridded: 3125 blocks x 16 nodes (8 blocks/CU),
// ytf padded [16][33] (R13 had a 16-way bank conflict on the stage writes:
// row stride 32 == 0 mod 32 banks). Weights staged once/block; t-loop inside;
// register accr[4]; plain store.
__global__ __launch_bounds__(256) void gate_acc_kernel(
    const __half2* __restrict__ yG,
    const float* __restrict__ Mz, const float* __restrict__ Bz,
    const float* __restrict__ Mh, const float* __restrict__ Bh,
    float* __restrict__ acc, int tbase, int nt) {
  __shared__ float sMz[IN_C * HID], sMh[IN_C * HID], sBz[HID], sBh[HID];
  __shared__ float ytf[GNB][IN_C + 1];  // +1 pad: stage writes spread banks
  int t = threadIdx.x;
  for (int i = t; i < IN_C * HID; i += 256) { sMz[i] = Mz[i]; sMh[i] = Mh[i]; }
  if (t < HID) { sBz[t] = Bz[t]; sBh[t] = Bh[t]; }
  int nb = blockIdx.x * GNB;  // NN % GNB == 0, no tail anywhere
  int j = t & 63;
  int w = t >> 6;
  int snn = t >> 4;   // staging: node 0..15
  int spr = t & 15;   // staging: half2 pair 0..15
  float accr[GNB / 4];
#pragma unroll
  for (int k = 0; k < GNB / 4; ++k) accr[k] = 0.f;

  for (int tl = 0; tl < nt; ++tl) {
    __syncthreads();  // prev gate reads done before ytf overwrite
    {
      // one half2 per thread: 16 nodes x 16 pairs, coalesced 64B/node row
      float2 f = __half22float2(yG[((size_t)tl * NN + nb + snn) * 16 + spr]);
      ytf[snn][spr * 2]     = f.x;
      ytf[snn][spr * 2 + 1] = f.y;
    }
    __syncthreads();
#pragma unroll
    for (int k = 0; k < GNB / 4; ++k) {
      int nl = (k << 2) | w;
      float za = sBz[j], ha = sBh[j];
#pragma unroll
      for (int c = 0; c < IN_C; ++c) {
        float yv = ytf[nl][c];  // wave-broadcast
        za += yv * sMz[c * HID + j];
        ha += yv * sMh[c * HID + j];
      }
      float z = 1.0f / (1.0f + expf(-za));
      accr[k] += (1.0f - z) * tanhf(ha);
    }
  }
#pragma unroll
  for (int k = 0; k < GNB / 4; ++k) {
    int n = nb + ((k << 2) | w);
    size_t ai = (size_t)n * HID + j;
    acc[ai] = (tbase == 0 ? 0.f : acc[ai]) + accr[k];
  }
}

// out[n][o] = (acc[n]/T) . W_out[:,o] + b_out[o]
__global__ __launch_bounds__(256) void out_kernel(const float* __restrict__ acc,
                                                  const float* __restrict__ W_out,
                                                  const float* __restrict__ b_out,
                                                  float* __restrict__ out) {
  __shared__ float sW[HID * OUT_C], sB[OUT_C];
  for (int i = threadIdx.x; i < HID * OUT_C; i += 256) sW[i] = W_out[i];
  if (threadIdx.x < OUT_C) sB[threadIdx.x] = b_out[threadIdx.x];
  __syncthreads();
  unsigned tid = blockIdx.x * 256u + threadIdx.x;
  unsigned n = tid >> 5;
  int o = tid & 31;
  if (n >= NN) return;
  const float* ar = acc + (size_t)n * HID;
  float v = 0.f;
#pragma unroll
  for (int k = 0; k < HID; ++k) v += ar[k] * sW[k * OUT_C + o];
  out[(size_t)n * OUT_C + o] = v * (1.0f / (float)TT) + sB[o];
}

static inline char* alignp(char* p, size_t a) {
  return (char*)(((size_t)p + a - 1) & ~(a - 1));
}

extern "C" void kernel_launch(void* const* d_in, const int* in_sizes, int n_in,
                              void* d_out, int out_size, void* d_ws, size_t ws_size,
                              hipStream_t stream) {
  const float* x     = (const float*)d_in[0];  // [T,N,32]
  const int*   ei    = (const int*)d_in[1];    // [T,2,E]
  const float* ew    = (const float*)d_in[2];  // [T,E]
  const float* Wz    = (const float*)d_in[3];
  const float* bz    = (const float*)d_in[4];
  // d_in[5..6] (Wr,br) dead: H==0 so R unused
  const float* Wh    = (const float*)d_in[7];
  const float* bh    = (const float*)d_in[8];
  const float* Lz_w  = (const float*)d_in[9];
  const float* Lz_b  = (const float*)d_in[10];
  // d_in[11..12] (Lr) dead
  const float* Lh_w  = (const float*)d_in[13];
  const float* Lh_b  = (const float*)d_in[14];
  const float* W_out = (const float*)d_in[15];
  const float* b_out = (const float*)d_in[16];
  float* out = (float*)d_out;

  // per-t sizes (bytes)
  const size_t binB   = (size_t)NB * CAP * 8;     // 10.0 MB (y aliases this: 3.2 MB/t)
  const size_t curB   = (size_t)NB * 4;
  const size_t bbB    = (size_t)NB * 4;
  const size_t dinvB  = (size_t)NN * 4;
  const size_t noffB  = (size_t)(NN + 1) * 4;
  const size_t sbufB  = (size_t)EE * 4;           // 3.2 MB
  const size_t perT   = binB + curB + bbB + dinvB + noffB + sbufB;  // ~13.6 MB
  const size_t xhB    = XPAIRS * 4;               // 38.4 MB
  const size_t fixedB = 4 * ((size_t)2 * IN_C * HID + 2 * HID)
                      + (size_t)NN * HID * 4 + xhB + 4096;  // ~51.3 MB

  int nt = 12;
  if (ws_size < fixedB + 12 * perT) {
    nt = (int)((ws_size - fixedB) / perT);
    if (nt < 1) nt = 1;
    if (nt > 12) nt = 12;
  }

  char* p = (char*)d_ws;
  unsigned long long* bin = (unsigned long long*)p;  // 8-aligned at base
  p += binB * nt;
  int* cursor = (int*)p;   p += curB * nt;
  int* bbase  = (int*)p;   p += bbB * nt;
  float* dinv = (float*)p; p += dinvB * nt;
  int* noffG  = (int*)p;   p += noffB * nt;
  unsigned* sbufG = (unsigned*)p; p += sbufB * nt;
  float* Mz = (float*)p;
  float* Mh = Mz + IN_C * HID;
  float* Bz = Mh + IN_C * HID;
  float* Bh = Bz + HID;
  float* acc = Bh + HID;  // [N,64]
  p = alignp((char*)(acc + (size_t)NN * HID), 256);
  __half2* xh = (__half2*)p;
  // y [nt,N,32] fp16 aliases the bin region: bin is dead after sort_kernel,
  // and stream order guarantees sort (reads bin) < gather_y (writes y) <
  // gate_acc (reads y) < next chunk's bin_kernel (rewrites bin).
  __half2* yG = (__half2*)bin;

  prep_kernel<<<dim3(IN_C + 1, 2), 64, 0, stream>>>(Wz, bz, Lz_w, Lz_b, Wh, bh,
                                                    Lh_w, Lh_b, Mz, Bz, Mh, Bh);
  xconv_kernel<<<(unsigned)((XPAIRS + 255) / 256), 256, 0, stream>>>(x, xh);

  for (int tb = 0; tb < TT; tb += nt) {
    int c = (TT - tb < nt) ? (TT - tb) : nt;
    hipMemsetAsync(cursor, 0, curB * c, stream);
    bin_kernel<<<dim3(ABLK, c), 256, 0, stream>>>(ei, ew, cursor, bin, tb);
    deg_kernel<<<dim3(NB, c), 256, 0, stream>>>(cursor, bin, dinv);
    bscan_kernel<<<c, 1024, 0, stream>>>(cursor, bbase);
    sort_kernel<<<dim3(NB, c), 256, 0, stream>>>(cursor, bbase, bin, dinv,
                                                 sbufG, noffG);
    gather_y_kernel<<<dim3(NN / 8, c), 256, 0, stream>>>(x, xh, dinv, noffG,
                                                         sbufG, yG, tb);
    gate_acc_kernel<<<NN / GNB, 256, 0, stream>>>(yG, Mz, Bz, Mh, Bh, acc, tb, c);
  }

  out_kernel<<<(NN * OUT_C + 255) / 256, 256, 0, stream>>>(acc, W_out, b_out, out);
}

// Round 15
// 826.425 us; speedup vs baseline: 1.2857x; 1.2857x over previous
//
#include <hip/hip_runtime.h>
#include <hip/hip_fp16.h>

#define NN 50000
#define TT 12
#define EE 800000
#define IN_C 32
#define HID 64
#define OUT_C 32
#define BSZ 64                        // nodes per bucket
#define NB ((NN + BSZ - 1) / BSZ)     // 782
#define CAP 1600                      // slots per (t,bucket); mean 1024
#define EPB 8192                      // edges per bin block
#define ABLK ((EE + EPB - 1) / EPB)   // 98
#define XPAIRS ((size_t)TT * NN * 16) // half2 elements in x

// ---------------- precompute folded gate matrices ----------------
// Mz = Wz @ Lz_w[:64] (32x64), Bz = bz @ Lz_w[:64] + Lz_b (64); same for h.
__global__ __launch_bounds__(64) void prep_kernel(
    const float* __restrict__ Wz, const float* __restrict__ bz,
    const float* __restrict__ Lzw, const float* __restrict__ Lzb,
    const float* __restrict__ Wh, const float* __restrict__ bh,
    const float* __restrict__ Lhw, const float* __restrict__ Lhb,
    float* __restrict__ Mz, float* __restrict__ Bz,
    float* __restrict__ Mh, float* __restrict__ Bh) {
  const int j = threadIdx.x;
  const int i = blockIdx.x;
  const int h = blockIdx.y;
  const float* W  = h ? Wh  : Wz;
  const float* b  = h ? bh  : bz;
  const float* L  = h ? Lhw : Lzw;
  const float* Lb = h ? Lhb : Lzb;
  float* M = h ? Mh : Mz;
  float* B = h ? Bh : Bz;
  if (i < IN_C) {
    float v = 0.f;
    for (int k = 0; k < HID; ++k) v += W[i * HID + k] * L[k * HID + j];
    M[i * HID + j] = v;
  } else {
    float v = Lb[j];
    for (int k = 0; k < HID; ++k) v += b[k] * L[k * HID + j];
    B[j] = v;
  }
}

// x [T,N,32] fp32 -> fp16 pairs
__global__ __launch_bounds__(256) void xconv_kernel(const float* __restrict__ x,
                                                    __half2* __restrict__ xh) {
  size_t i = (size_t)blockIdx.x * 256 + threadIdx.x;
  if (i < XPAIRS) {
    float2 f = ((const float2*)x)[i];
    xh[i] = __floats2half2_rn(f.x, f.y);
  }
}

// Pass A: coarse-bucket multisplit (proven R8-R13).
// Entries {src16 | (dst&63)<<16 | w16<<32} bucket-grouped.
__global__ __launch_bounds__(256) void bin_kernel(const int* __restrict__ ei,
                                                  const float* __restrict__ ew,
                                                  int* __restrict__ cursorA,
                                                  unsigned long long* __restrict__ binA,
                                                  int tbase) {
  __shared__ int hist[NB];
  __shared__ int rnk[NB];
  int tl = blockIdx.y;
  const int* src = ei + (size_t)(tbase + tl) * 2 * EE;
  const int* dst = src + EE;
  const float* w = ew + (size_t)(tbase + tl) * EE;
  int* cursor = cursorA + (size_t)tl * NB;
  unsigned long long* bin = binA + (size_t)tl * NB * CAP;
  int t = threadIdx.x;
  for (int i = t; i < NB; i += 256) { hist[i] = 0; rnk[i] = 0; }
  __syncthreads();
  int e0 = blockIdx.x * EPB;
#pragma unroll
  for (int i = 0; i < EPB / 256; ++i) {
    int e = e0 + i * 256 + t;
    if (e < EE) atomicAdd(&hist[dst[e] >> 6], 1);
  }
  __syncthreads();
  for (int b = t; b < NB; b += 256)
    hist[b] = atomicAdd(&cursor[b], hist[b]);  // hist becomes this block's base
  __syncthreads();
#pragma unroll
  for (int i = 0; i < EPB / 256; ++i) {
    int e = e0 + i * 256 + t;
    if (e < EE) {
      int d = dst[e], s = src[e];
      int b = d >> 6;
      unsigned short hw = __half_as_ushort(__float2half_rn(w[e]));
      int pos = hist[b] + atomicAdd(&rnk[b], 1);
      if (pos < CAP)
        bin[(size_t)b * CAP + pos] =
            (unsigned long long)((unsigned)s | ((unsigned)(d & 63) << 16)) |
            ((unsigned long long)hw << 32);
    }
  }
}

// per (bucket,t): deg = 1 + sum w over bucket entries, dinv = rsqrt(deg)
__global__ __launch_bounds__(256) void deg_kernel(const int* __restrict__ cursorA,
                                                  const unsigned long long* __restrict__ binA,
                                                  float* __restrict__ dinvA) {
  __shared__ float wsum[BSZ];
  int tl = blockIdx.y, b = blockIdx.x;
  int t = threadIdx.x;
  if (t < BSZ) wsum[t] = 0.f;
  __syncthreads();
  int cnt = min(cursorA[(size_t)tl * NB + b], CAP);
  const unsigned long long* bin = binA + ((size_t)tl * NB + b) * CAP;
  for (int i = t; i < cnt; i += 256) {
    unsigned long long u = bin[i];
    int dl = (int)((u >> 16) & 63u);
    float wv = __half2float(__ushort_as_half((unsigned short)(u >> 32)));
    atomicAdd(&wsum[dl], wv);
  }
  __syncthreads();
  int n = b * BSZ + t;
  if (t < BSZ && n < NN) dinvA[(size_t)tl * NN + n] = rsqrtf(1.0f + wsum[t]);
}

// exclusive scan of clamped bucket counts -> bucket bases (per t)
__global__ __launch_bounds__(1024) void bscan_kernel(const int* __restrict__ cursorA,
                                                     int* __restrict__ bbaseA) {
  __shared__ int s[1024];
  int tl = blockIdx.x, t = threadIdx.x;
  int v = (t < NB) ? min(cursorA[(size_t)tl * NB + t], CAP) : 0;
  s[t] = v;
  __syncthreads();
  for (int o = 1; o < 1024; o <<= 1) {
    int u = (t >= o) ? s[t - o] : 0;
    __syncthreads();
    s[t] += u;
    __syncthreads();
  }
  if (t < NB) bbaseA[(size_t)tl * NB + t] = s[t] - v;  // exclusive
}

// per (bucket,t): counting-sort bucket entries by dst&63 into global CSR
// sbufG {src16 | fp16(w*dinv[src])<<16}; write noffG per node.
__global__ __launch_bounds__(256) void sort_kernel(
    const int* __restrict__ cursorA, const int* __restrict__ bbaseA,
    const unsigned long long* __restrict__ binA, const float* __restrict__ dinvA,
    unsigned* __restrict__ sbufG, int* __restrict__ noffG) {
  __shared__ int hist[BSZ + 1];
  __shared__ int plc[BSZ];
  int tl = blockIdx.y, b = blockIdx.x;
  int t = threadIdx.x;
  if (t < BSZ + 1) hist[t] = 0;
  __syncthreads();
  int cnt = min(cursorA[(size_t)tl * NB + b], CAP);
  int base = bbaseA[(size_t)tl * NB + b];
  const unsigned long long* bin = binA + ((size_t)tl * NB + b) * CAP;
  const float* dinv = dinvA + (size_t)tl * NN;
  unsigned* sbuf = sbufG + (size_t)tl * EE;
  int* noff = noffG + (size_t)tl * (NN + 1);
  for (int e = t; e < cnt; e += 256)
    atomicAdd(&hist[(int)((bin[e] >> 16) & 63u)], 1);
  __syncthreads();
  if (t == 0) {
    int run = 0;
#pragma unroll
    for (int i = 0; i < BSZ; ++i) {
      int c = hist[i];
      hist[i] = run;
      plc[i] = run;
      run += c;
    }
    hist[BSZ] = run;
    if (b == NB - 1) noff[NN] = base + run;
  }
  __syncthreads();
  {
    int n = b * BSZ + t;
    if (t < BSZ && n < NN) noff[n] = base + hist[t];
  }
  for (int e = t; e < cnt; e += 256) {
    unsigned long long u = bin[e];
    int s = (int)(u & 0xFFFFu);
    int dl = (int)((u >> 16) & 63u);
    float nm = __half2float(__ushort_as_half((unsigned short)(u >> 32))) * dinv[s];
    int pos = base + atomicAdd(&plc[dl], 1);
    sbuf[pos] = (unsigned)s | ((unsigned)__half_as_ushort(__float2half_rn(nm)) << 16);
  }
}

// Pass B1: pure gather, NO LDS / NO barriers (proven R13). t-major grid
// (blockIdx.y = t) keeps xh_t L2-resident. Wave = 2 nodes; writes y fp16.
__global__ __launch_bounds__(256) void gather_y_kernel(
    const float* __restrict__ x, const __half2* __restrict__ xh,
    const float* __restrict__ dinvA, const int* __restrict__ noffG,
    const unsigned* __restrict__ sbufG, __half2* __restrict__ yG, int tbase) {
  int t = threadIdx.x;
  int w = t >> 6;        // wave 0..3
  int lane = t & 63;
  int h2 = lane >> 5;    // node half 0/1
  int sl = lane & 31;
  int g = sl >> 3;       // edge group 0..3
  int cl = sl & 7;       // channel quad 0..7
  int tl = blockIdx.y;
  int n = blockIdx.x * 8 + w * 2 + h2;  // NN % 8 == 0, no tail

  const float* dinv = dinvA + (size_t)tl * NN;
  const int* noff = noffG + (size_t)tl * (NN + 1);
  const unsigned* sbuf = sbufG + (size_t)tl * EE;
  const __half2* xht = xh + (size_t)(tbase + tl) * NN * 16;
  const float* xt = x + (size_t)(tbase + tl) * NN * IN_C;

  int e0 = noff[n], e1 = noff[n + 1];
  float4 v = {0.f, 0.f, 0.f, 0.f};
  for (int e = e0 + g; e < e1; e += 4) {
    unsigned u = sbuf[e];  // 8 lanes same addr: broadcast
    float nm = __half2float(__ushort_as_half((unsigned short)(u >> 16)));
    uint2 xr = ((const uint2*)(xht + (size_t)(u & 0xFFFFu) * 16))[cl];
    float2 p0 = __half22float2(*(const __half2*)&xr.x);
    float2 p1 = __half22float2(*(const __half2*)&xr.y);
    v.x += nm * p0.x; v.y += nm * p0.y;
    v.z += nm * p1.x; v.w += nm * p1.y;
  }
  // reduce over the 4 edge groups (lane bits 3,4 — stays within node half)
  v.x += __shfl_xor(v.x, 8);  v.y += __shfl_xor(v.y, 8);
  v.z += __shfl_xor(v.z, 8);  v.w += __shfl_xor(v.w, 8);
  v.x += __shfl_xor(v.x, 16); v.y += __shfl_xor(v.y, 16);
  v.z += __shfl_xor(v.z, 16); v.w += __shfl_xor(v.w, 16);
  if (g == 0) {  // 8 lanes per node x float4 = all 32 channels
    float dv = dinv[n];
    float4 xs = ((const float4*)(xt + (size_t)n * IN_C))[cl];  // fp32 self-loop
    __half2 o0 = __floats2half2_rn(dv * (v.x + dv * xs.x), dv * (v.y + dv * xs.y));
    __half2 o1 = __floats2half2_rn(dv * (v.z + dv * xs.z), dv * (v.w + dv * xs.w));
    __half2* yp = yG + ((size_t)tl * NN + n) * 16 + cl * 2;
    yp[0] = o0;
    yp[1] = o1;
  }
}

// Pass B2: gate, t-PARALLEL grid (782 x nt) — R13's 64-node tile (proven
// 288us) with its two defects fixed: staging pad [64][33] (R13: 600k bank
// conflicts) and t in the grid (R13: 782 blocks, 12-deep serial t-loop).
// No accr array (R14's regrid bloated VGPR 60->144); each thread computes
// 16 gate evals and atomicAdds into acc (R12 proved coalesced fp32 atomics
// at this layout are cheap). acc memset once per launch.
__global__ __launch_bounds__(256) void gate_acc_kernel(
    const __half2* __restrict__ yG,
    const float* __restrict__ Mz, const float* __restrict__ Bz,
    const float* __restrict__ Mh, const float* __restrict__ Bh,
    float* __restrict__ acc) {
  __shared__ float sMz[IN_C * HID], sMh[IN_C * HID], sBz[HID], sBh[HID];
  __shared__ float ytf[BSZ][IN_C + 1];  // +1 pad: stage writes spread banks
  int t = threadIdx.x;
  for (int i = t; i < IN_C * HID; i += 256) { sMz[i] = Mz[i]; sMh[i] = Mh[i]; }
  if (t < HID) { sBz[t] = Bz[t]; sBh[t] = Bh[t]; }
  int tl = blockIdx.y;
  int nb = blockIdx.x * BSZ;
  // stage y tile: one uint4 (8 ch) per thread; node = t>>2, quad = t&3
  {
    int snn = nb + (t >> 2);
    int q = t & 3;
    if (snn < NN) {
      uint4 qv = *(const uint4*)(yG + ((size_t)tl * NN + snn) * 16 + q * 4);
      const __half2* hp = (const __half2*)&qv;
#pragma unroll
      for (int i = 0; i < 4; ++i) {
        float2 f = __half22float2(hp[i]);
        ytf[t >> 2][q * 8 + 2 * i]     = f.x;
        ytf[t >> 2][q * 8 + 2 * i + 1] = f.y;
      }
    }
  }
  __syncthreads();
  int j = t & 63;
  int w = t >> 6;
#pragma unroll
  for (int k = 0; k < 16; ++k) {
    int nl = (k << 2) | w;
    int n = nb + nl;
    if (n < NN) {
      float za = sBz[j], ha = sBh[j];
#pragma unroll
      for (int c = 0; c < IN_C; ++c) {
        float yv = ytf[nl][c];  // wave-broadcast
        za += yv * sMz[c * HID + j];
        ha += yv * sMh[c * HID + j];
      }
      float z = 1.0f / (1.0f + expf(-za));
      atomicAdd(&acc[(size_t)n * HID + j], (1.0f - z) * tanhf(ha));
    }
  }
}

// out[n][o] = (acc[n]/T) . W_out[:,o] + b_out[o]
__global__ __launch_bounds__(256) void out_kernel(const float* __restrict__ acc,
                                                  const float* __restrict__ W_out,
                                                  const float* __restrict__ b_out,
                                                  float* __restrict__ out) {
  __shared__ float sW[HID * OUT_C], sB[OUT_C];
  for (int i = threadIdx.x; i < HID * OUT_C; i += 256) sW[i] = W_out[i];
  if (threadIdx.x < OUT_C) sB[threadIdx.x] = b_out[threadIdx.x];
  __syncthreads();
  unsigned tid = blockIdx.x * 256u + threadIdx.x;
  unsigned n = tid >> 5;
  int o = tid & 31;
  if (n >= NN) return;
  const float* ar = acc + (size_t)n * HID;
  float v = 0.f;
#pragma unroll
  for (int k = 0; k < HID; ++k) v += ar[k] * sW[k * OUT_C + o];
  out[(size_t)n * OUT_C + o] = v * (1.0f / (float)TT) + sB[o];
}

static inline char* alignp(char* p, size_t a) {
  return (char*)(((size_t)p + a - 1) & ~(a - 1));
}

extern "C" void kernel_launch(void* const* d_in, const int* in_sizes, int n_in,
                              void* d_out, int out_size, void* d_ws, size_t ws_size,
                              hipStream_t stream) {
  const float* x     = (const float*)d_in[0];  // [T,N,32]
  const int*   ei    = (const int*)d_in[1];    // [T,2,E]
  const float* ew    = (const float*)d_in[2];  // [T,E]
  const float* Wz    = (const float*)d_in[3];
  const float* bz    = (const float*)d_in[4];
  // d_in[5..6] (Wr,br) dead: H==0 so R unused
  const float* Wh    = (const float*)d_in[7];
  const float* bh    = (const float*)d_in[8];
  const float* Lz_w  = (const float*)d_in[9];
  const float* Lz_b  = (const float*)d_in[10];
  // d_in[11..12] (Lr) dead
  const float* Lh_w  = (const float*)d_in[13];
  const float* Lh_b  = (const float*)d_in[14];
  const float* W_out = (const float*)d_in[15];
  const float* b_out = (const float*)d_in[16];
  float* out = (float*)d_out;

  // per-t sizes (bytes)
  const size_t binB   = (size_t)NB * CAP * 8;     // 10.0 MB (y aliases this: 3.2 MB/t)
  const size_t curB   = (size_t)NB * 4;
  const size_t bbB    = (size_t)NB * 4;
  const size_t dinvB  = (size_t)NN * 4;
  const size_t noffB  = (size_t)(NN + 1) * 4;
  const size_t sbufB  = (size_t)EE * 4;           // 3.2 MB
  const size_t perT   = binB + curB + bbB + dinvB + noffB + sbufB;  // ~13.6 MB
  const size_t xhB    = XPAIRS * 4;               // 38.4 MB
  const size_t fixedB = 4 * ((size_t)2 * IN_C * HID + 2 * HID)
                      + (size_t)NN * HID * 4 + xhB + 4096;  // ~51.3 MB

  int nt = 12;
  if (ws_size < fixedB + 12 * perT) {
    nt = (int)((ws_size - fixedB) / perT);
    if (nt < 1) nt = 1;
    if (nt > 12) nt = 12;
  }

  char* p = (char*)d_ws;
  unsigned long long* bin = (unsigned long long*)p;  // 8-aligned at base
  p += binB * nt;
  int* cursor = (int*)p;   p += curB * nt;
  int* bbase  = (int*)p;   p += bbB * nt;
  float* dinv = (float*)p; p += dinvB * nt;
  int* noffG  = (int*)p;   p += noffB * nt;
  unsigned* sbufG = (unsigned*)p; p += sbufB * nt;
  float* Mz = (float*)p;
  float* Mh = Mz + IN_C * HID;
  float* Bz = Mh + IN_C * HID;
  float* Bh = Bz + HID;
  float* acc = Bh + HID;  // [N,64]
  p = alignp((char*)(acc + (size_t)NN * HID), 256);
  __half2* xh = (__half2*)p;
  // y [nt,N,32] fp16 aliases the bin region: bin is dead after sort_kernel,
  // and stream order guarantees sort (reads bin) < gather_y (writes y) <
  // gate_acc (reads y) < next chunk's bin_kernel (rewrites bin).
  __half2* yG = (__half2*)bin;

  prep_kernel<<<dim3(IN_C + 1, 2), 64, 0, stream>>>(Wz, bz, Lz_w, Lz_b, Wh, bh,
                                                    Lh_w, Lh_b, Mz, Bz, Mh, Bh);
  xconv_kernel<<<(unsigned)((XPAIRS + 255) / 256), 256, 0, stream>>>(x, xh);
  hipMemsetAsync(acc, 0, (size_t)NN * HID * sizeof(float), stream);

  for (int tb = 0; tb < TT; tb += nt) {
    int c = (TT - tb < nt) ? (TT - tb) : nt;
    hipMemsetAsync(cursor, 0, curB * c, stream);
    bin_kernel<<<dim3(ABLK, c), 256, 0, stream>>>(ei, ew, cursor, bin, tb);
    deg_kernel<<<dim3(NB, c), 256, 0, stream>>>(cursor, bin, dinv);
    bscan_kernel<<<c, 1024, 0, stream>>>(cursor, bbase);
    sort_kernel<<<dim3(NB, c), 256, 0, stream>>>(cursor, bbase, bin, dinv,
                                                 sbufG, noffG);
    gather_y_kernel<<<dim3(NN / 8, c), 256, 0, stream>>>(x, xh, dinv, noffG,
                                                         sbufG, yG, tb);
    gate_acc_kernel<<<dim3(NB, c), 256, 0, stream>>>(yG, Mz, Bz, Mh, Bh, acc);
  }

  out_kernel<<<(NN * OUT_C + 255) / 256, 256, 0, stream>>>(acc, W_out, b_out, out);
}